// Round 1
// baseline (1306.296 us; speedup 1.0000x reference)
//
#include <hip/hip_runtime.h>
#include <math.h>

#define Bn   2048
#define Ln   200
#define En   64
#define Vn   100000
#define FEATn 1664
#define LT   32      // attention l sub-tile
#define LPAD 224     // 7 * 32

// ---------------- block-wide reductions (256 threads = 4 waves) -------------
__device__ __forceinline__ float blk_sum(float v, float* shred) {
  #pragma unroll
  for (int o = 32; o > 0; o >>= 1) v += __shfl_down(v, o, 64);
  const int t = threadIdx.x;
  __syncthreads();
  if ((t & 63) == 0) shred[t >> 6] = v;
  __syncthreads();
  return shred[0] + shred[1] + shred[2] + shred[3];
}
__device__ __forceinline__ float blk_max(float v, float* shred) {
  #pragma unroll
  for (int o = 32; o > 0; o >>= 1) v = fmaxf(v, __shfl_down(v, o, 64));
  const int t = threadIdx.x;
  __syncthreads();
  if ((t & 63) == 0) shred[t >> 6] = v;
  __syncthreads();
  return fmaxf(fmaxf(shred[0], shred[1]), fmaxf(shred[2], shred[3]));
}

// ---------------- K1: small gathers + numeric projections -------------------
__global__ __launch_bounds__(256) void k_gather(
    const int* __restrict__ user_cat, const float* __restrict__ user_num,
    const int* __restrict__ ctx_cat,  const float* __restrict__ ctx_num,
    const int* __restrict__ item_cat, const float* __restrict__ item_num,
    const float* __restrict__ user_emb, const float* __restrict__ item_emb,
    const float* __restrict__ ctx_emb,
    const float* __restrict__ Wu, const float* __restrict__ bu,
    const float* __restrict__ Wi, const float* __restrict__ bi,
    const float* __restrict__ Wc, const float* __restrict__ bc,
    float* __restrict__ base)
{
  const int b = blockIdx.x;
  float* out = base + (size_t)b * FEATn;
  for (int f = threadIdx.x; f < 1344; f += 256) {
    float v;
    if (f < 384) {                       // user_g
      int n = f >> 6, e = f & 63;
      int id = user_cat[b * 6 + n];
      v = user_emb[((size_t)n * Vn + id) * 64 + e];
    } else if (f < 896) {                // item_g
      int g = f - 384; int n = g >> 6, e = g & 63;
      int id = item_cat[b * 8 + n];
      v = item_emb[((size_t)n * Vn + id) * 64 + e];
    } else if (f < 1152) {               // ctx_g
      int g = f - 896; int n = g >> 6, e = g & 63;
      int id = ctx_cat[b * 4 + n];
      v = ctx_emb[((size_t)n * Vn + id) * 64 + e];
    } else {                             // numeric projections (relu)
      int g = f - 1152; int wch = g >> 6, e = g & 63;
      float s;
      if (wch == 0) {
        s = bu[e];
        #pragma unroll
        for (int d = 0; d < 8; d++) s += user_num[b * 8 + d] * Wu[d * 64 + e];
      } else if (wch == 1) {
        s = bi[e];
        #pragma unroll
        for (int d = 0; d < 6; d++) s += item_num[b * 6 + d] * Wi[d * 64 + e];
      } else {
        s = bc[e];
        #pragma unroll
        for (int d = 0; d < 4; d++) s += ctx_num[b * 4 + d] * Wc[d * 64 + e];
      }
      v = fmaxf(s, 0.f);
    }
    out[f] = v;
  }
}

// ---------------- K2: fused DIN attention + softmax + hist_att + pools ------
// One block per b. Folded layer-1: h1 = qterm + h@(A1[64:128]-A1[128:192]) + (q*h)@A1[192:256]
__global__ __launch_bounds__(256) void k_attn(
    const int* __restrict__ hist_ids, const int* __restrict__ hist_author,
    const int* __restrict__ hist_tag, const int* __restrict__ hist_mask,
    const float* __restrict__ item_emb,
    const float* __restrict__ A1, const float* __restrict__ a1,
    const float* __restrict__ A2, const float* __restrict__ a2,
    const float* __restrict__ A3, const float* __restrict__ a3,
    float* __restrict__ base)
{
  const int b = blockIdx.x;
  const int t = threadIdx.x;

  __shared__ float sh_q[64];
  __shared__ float sh_qterm[256];
  __shared__ float sh_Xt[LT][129];   // k<64: h ; k>=64: q*h
  __shared__ float sh_H1[LT][257];
  __shared__ float sh_H2[LT][129];
  __shared__ float sh_score[LPAD];
  __shared__ float sh_maskf[LPAD];
  __shared__ float sh_red[12][64];
  __shared__ float shred[4];

  const float* item0 = item_emb;                        // table 0 (videos)
  const float* itemA = item_emb + (size_t)1 * Vn * 64;  // table 1 (authors)
  const float* itemT = item_emb + (size_t)7 * Vn * 64;  // table 7 (tags)
  const int* hid = hist_ids + b * Ln;

  if (t < 64)  sh_q[t] = base[(size_t)b * FEATn + 384 + t];  // target video
  if (t < LPAD) sh_maskf[t] = (t < Ln && hist_mask[b * Ln + t] > 0) ? 1.f : 0.f;
  __syncthreads();

  { // per-b qterm[j] = a1[j] + sum_e q[e]*(A1[e][j] + A1[128+e][j])
    float s = a1[t];
    for (int e = 0; e < 64; e++)
      s += sh_q[e] * (A1[e * 256 + t] + A1[(128 + e) * 256 + t]);
    sh_qterm[t] = s;
  }
  __syncthreads();

  const int tx = t & 31, ty = t >> 5;   // layer1: cols tx*8, rows ty*4

  for (int l0 = 0; l0 < LPAD; l0 += LT) {
    // ---- gather hist rows + build Xt -----------------------------------
    #pragma unroll
    for (int i = 0; i < 2; i++) {
      int idx = t + i * 256;              // 512 float4 total
      int r = idx >> 4, e4 = (idx & 15) << 2;
      int l = l0 + r; int le = (l < Ln) ? l : (Ln - 1);
      size_t row = (size_t)hid[le] * 64;
      float4 h4 = *(const float4*)(item0 + row + e4);
      sh_Xt[r][e4 + 0] = h4.x;  sh_Xt[r][64 + e4 + 0] = sh_q[e4 + 0] * h4.x;
      sh_Xt[r][e4 + 1] = h4.y;  sh_Xt[r][64 + e4 + 1] = sh_q[e4 + 1] * h4.y;
      sh_Xt[r][e4 + 2] = h4.z;  sh_Xt[r][64 + e4 + 2] = sh_q[e4 + 2] * h4.z;
      sh_Xt[r][e4 + 3] = h4.w;  sh_Xt[r][64 + e4 + 3] = sh_q[e4 + 3] * h4.w;
    }
    __syncthreads();

    // ---- layer 1: 32x256, K=128 ----------------------------------------
    float acc[4][8];
    #pragma unroll
    for (int r = 0; r < 4; r++)
      #pragma unroll
      for (int c = 0; c < 8; c++) acc[r][c] = sh_qterm[tx * 8 + c];

    for (int kk = 0; kk < 64; kk++) {
      const float* p1 = A1 + (64 + kk) * 256 + tx * 8;
      const float* p2 = A1 + (128 + kk) * 256 + tx * 8;
      float4 wa0 = *(const float4*)p1, wa1 = *(const float4*)(p1 + 4);
      float4 wb0 = *(const float4*)p2, wb1 = *(const float4*)(p2 + 4);
      float w[8] = {wa0.x - wb0.x, wa0.y - wb0.y, wa0.z - wb0.z, wa0.w - wb0.w,
                    wa1.x - wb1.x, wa1.y - wb1.y, wa1.z - wb1.z, wa1.w - wb1.w};
      float x[4];
      #pragma unroll
      for (int r = 0; r < 4; r++) x[r] = sh_Xt[ty * 4 + r][kk];
      #pragma unroll
      for (int r = 0; r < 4; r++)
        #pragma unroll
        for (int c = 0; c < 8; c++) acc[r][c] += x[r] * w[c];
    }
    for (int kk = 0; kk < 64; kk++) {
      const float* p1 = A1 + (192 + kk) * 256 + tx * 8;
      float4 wa0 = *(const float4*)p1, wa1 = *(const float4*)(p1 + 4);
      float w[8] = {wa0.x, wa0.y, wa0.z, wa0.w, wa1.x, wa1.y, wa1.z, wa1.w};
      float x[4];
      #pragma unroll
      for (int r = 0; r < 4; r++) x[r] = sh_Xt[ty * 4 + r][64 + kk];
      #pragma unroll
      for (int r = 0; r < 4; r++)
        #pragma unroll
        for (int c = 0; c < 8; c++) acc[r][c] += x[r] * w[c];
    }
    #pragma unroll
    for (int r = 0; r < 4; r++)
      #pragma unroll
      for (int c = 0; c < 8; c++)
        sh_H1[ty * 4 + r][tx * 8 + c] = fmaxf(acc[r][c], 0.f);
    __syncthreads();

    // ---- layer 2: 32x128, K=256 ----------------------------------------
    float acc2[4][4];
    {
      float4 bz = *(const float4*)(a2 + tx * 4);
      #pragma unroll
      for (int r = 0; r < 4; r++) {
        acc2[r][0] = bz.x; acc2[r][1] = bz.y; acc2[r][2] = bz.z; acc2[r][3] = bz.w;
      }
    }
    for (int k = 0; k < 256; k++) {
      float4 w = *(const float4*)(A2 + k * 128 + tx * 4);
      float x[4];
      #pragma unroll
      for (int r = 0; r < 4; r++) x[r] = sh_H1[ty * 4 + r][k];
      #pragma unroll
      for (int r = 0; r < 4; r++) {
        acc2[r][0] += x[r] * w.x; acc2[r][1] += x[r] * w.y;
        acc2[r][2] += x[r] * w.z; acc2[r][3] += x[r] * w.w;
      }
    }
    #pragma unroll
    for (int r = 0; r < 4; r++)
      #pragma unroll
      for (int c = 0; c < 4; c++)
        sh_H2[ty * 4 + r][tx * 4 + c] = fmaxf(acc2[r][c], 0.f);
    __syncthreads();

    // ---- layer 3: 32 scores, K=128 --------------------------------------
    {
      int l = t >> 3, seg = t & 7;
      float p = 0.f;
      #pragma unroll
      for (int i = 0; i < 16; i++)
        p += sh_H2[l][seg * 16 + i] * A3[seg * 16 + i];
      sh_red[seg][l] = p;   // seg<8, l<32
    }
    __syncthreads();
    if (t < 32) {
      float s = a3[0];
      #pragma unroll
      for (int g = 0; g < 8; g++) s += sh_red[g][t];
      sh_score[l0 + t] = s;
    }
    __syncthreads();
  }

  // ---- softmax (masked) + renorm ---------------------------------------
  float v = -3.0e38f;
  if (t < LPAD && sh_maskf[t] > 0.f) v = sh_score[t];
  float m = blk_max(v, shred);
  float ev = 0.f;
  if (t < LPAD && sh_maskf[t] > 0.f) ev = expf(sh_score[t] - m);
  float S = blk_sum(ev, shred);
  float nvalid = blk_sum((t < LPAD) ? sh_maskf[t] : 0.f, shred);
  float invS = 1.f / fmaxf(S, 1e-30f);
  if (t < LPAD) sh_score[t] = ev * invS;    // sh_score now holds w
  __syncthreads();

  // ---- hist_att + author/tag pools (second gather pass) -----------------
  {
    const int e = t & 63, lg = t >> 6;
    const int* haid = hist_author + b * Ln;
    const int* htid = hist_tag + b * Ln;
    float aw = 0.f, aa = 0.f, atg = 0.f;
    for (int l = lg; l < Ln; l += 4) {      // l wave-uniform
      float mf = sh_maskf[l];
      if (mf > 0.f) {
        float w = sh_score[l];
        aw  += w * item0[(size_t)hid[l] * 64 + e];
        aa  += itemA[(size_t)haid[l] * 64 + e];
        atg += itemT[(size_t)htid[l] * 64 + e];
      }
    }
    sh_red[lg][e] = aw; sh_red[4 + lg][e] = aa; sh_red[8 + lg][e] = atg;
  }
  __syncthreads();
  if (t < 64) {
    float ha = 0.f, ap = 0.f, tp = 0.f;
    #pragma unroll
    for (int g = 0; g < 4; g++) {
      ha += sh_red[g][t]; ap += sh_red[4 + g][t]; tp += sh_red[8 + g][t];
    }
    float inv = 1.f / fmaxf(nvalid, 1e-6f);
    ap *= inv; tp *= inv;
    float tv = sh_q[t];
    float* out = base + (size_t)b * FEATn;
    out[1344 + t] = ha;
    out[1408 + t] = ap;
    out[1472 + t] = tp;
    out[1536 + t] = tv * ha;
    out[1600 + t] = tv - ha;
  }
}

// ---------------- K3: generic fp32 tiled GEMM  C = act(A@W + bias) ----------
// A: MxK row-major, W: KxN row-major. BM=BN=64, BK=32, 256 threads.
__global__ __launch_bounds__(256) void k_gemm(
    const float* __restrict__ A, const float* __restrict__ W,
    const float* __restrict__ bias, float* __restrict__ C,
    int N, int K, int relu)
{
  __shared__ float As[64][33];
  __shared__ float Ws[32][64];
  const int t = threadIdx.x;
  const int m0 = blockIdx.x * 64, n0 = blockIdx.y * 64;
  const int tx = t & 15, ty = t >> 4;     // cols tx*4, rows ty*4
  float acc[4][4] = {{0.f}};

  for (int k0 = 0; k0 < K; k0 += 32) {
    #pragma unroll
    for (int i = 0; i < 2; i++) {          // A tile 64x32
      int idx = t + i * 256;
      int r = idx >> 3, kq = (idx & 7) << 2;
      float4 a4 = *(const float4*)(A + (size_t)(m0 + r) * K + k0 + kq);
      As[r][kq + 0] = a4.x; As[r][kq + 1] = a4.y;
      As[r][kq + 2] = a4.z; As[r][kq + 3] = a4.w;
    }
    #pragma unroll
    for (int i = 0; i < 2; i++) {          // W tile 32x64
      int idx = t + i * 256;
      int kk = idx >> 4, c4 = (idx & 15) << 2;
      float4 w4 = *(const float4*)(W + (size_t)(k0 + kk) * N + n0 + c4);
      *(float4*)&Ws[kk][c4] = w4;
    }
    __syncthreads();
    #pragma unroll
    for (int kk = 0; kk < 32; kk++) {
      float a0 = As[ty * 4 + 0][kk], a1v = As[ty * 4 + 1][kk];
      float a2v = As[ty * 4 + 2][kk], a3v = As[ty * 4 + 3][kk];
      float4 w = *(const float4*)&Ws[kk][tx * 4];
      acc[0][0] += a0 * w.x; acc[0][1] += a0 * w.y; acc[0][2] += a0 * w.z; acc[0][3] += a0 * w.w;
      acc[1][0] += a1v * w.x; acc[1][1] += a1v * w.y; acc[1][2] += a1v * w.z; acc[1][3] += a1v * w.w;
      acc[2][0] += a2v * w.x; acc[2][1] += a2v * w.y; acc[2][2] += a2v * w.z; acc[2][3] += a2v * w.w;
      acc[3][0] += a3v * w.x; acc[3][1] += a3v * w.y; acc[3][2] += a3v * w.z; acc[3][3] += a3v * w.w;
    }
    __syncthreads();
  }
  float4 bz = *(const float4*)(bias + n0 + tx * 4);
  #pragma unroll
  for (int r = 0; r < 4; r++) {
    float4 o;
    o.x = acc[r][0] + bz.x; o.y = acc[r][1] + bz.y;
    o.z = acc[r][2] + bz.z; o.w = acc[r][3] + bz.w;
    if (relu) {
      o.x = fmaxf(o.x, 0.f); o.y = fmaxf(o.y, 0.f);
      o.z = fmaxf(o.z, 0.f); o.w = fmaxf(o.w, 0.f);
    }
    *(float4*)(C + (size_t)(m0 + ty * 4 + r) * N + n0 + tx * 4) = o;
  }
}

// ---------------- K4: DCN cross (3 iters) + final head ----------------------
__global__ __launch_bounds__(256) void k_cross_final(
    const float* __restrict__ base, const float* __restrict__ cross_w,
    const float* __restrict__ cross_b, const float* __restrict__ deep3,
    const float* __restrict__ Wh, const float* __restrict__ bh,
    float* __restrict__ out)
{
  __shared__ float shred[4];
  const int b = blockIdx.x, t = threadIdx.x;
  const float* br = base + (size_t)b * FEATn;
  float bs[7], xl[7];
  #pragma unroll
  for (int j = 0; j < 7; j++) {
    int i = t + j * 256;
    float v = (i < FEATn) ? br[i] : 0.f;
    bs[j] = v; xl[j] = v;
  }
  for (int k = 0; k < 3; k++) {
    float p = 0.f;
    #pragma unroll
    for (int j = 0; j < 7; j++) {
      int i = t + j * 256;
      if (i < FEATn) p += xl[j] * cross_w[k * FEATn + i];
    }
    float xw = blk_sum(p, shred);
    #pragma unroll
    for (int j = 0; j < 7; j++) {
      int i = t + j * 256;
      if (i < FEATn) xl[j] = bs[j] * xw + cross_b[k * FEATn + i] + xl[j];
    }
  }
  float p = 0.f;
  #pragma unroll
  for (int j = 0; j < 7; j++) {
    int i = t + j * 256;
    if (i < FEATn) p += xl[j] * Wh[i];
  }
  p += deep3[(size_t)b * 256 + t] * Wh[FEATn + t];
  float tot = blk_sum(p, shred);
  if (t == 0) out[b] = tot + bh[0];
}

// ---------------- launch -----------------------------------------------------
extern "C" void kernel_launch(void* const* d_in, const int* in_sizes, int n_in,
                              void* d_out, int out_size, void* d_ws, size_t ws_size,
                              hipStream_t stream) {
  (void)in_sizes; (void)n_in; (void)out_size; (void)ws_size;
  const int*   user_cat  = (const int*)d_in[0];
  const float* user_num  = (const float*)d_in[1];
  const int*   ctx_cat   = (const int*)d_in[2];
  const float* ctx_num   = (const float*)d_in[3];
  const int*   hist_ids  = (const int*)d_in[4];
  const int*   hist_auth = (const int*)d_in[5];
  const int*   hist_tag  = (const int*)d_in[6];
  const int*   hist_mask = (const int*)d_in[7];
  const int*   item_cat  = (const int*)d_in[8];
  const float* item_num  = (const float*)d_in[9];
  const float* user_emb  = (const float*)d_in[10];
  const float* item_emb  = (const float*)d_in[11];
  const float* ctx_emb   = (const float*)d_in[12];
  const float* Wu = (const float*)d_in[13];  const float* bu = (const float*)d_in[14];
  const float* Wi = (const float*)d_in[15];  const float* bi = (const float*)d_in[16];
  const float* Wc = (const float*)d_in[17];  const float* bc = (const float*)d_in[18];
  const float* A1 = (const float*)d_in[19];  const float* a1 = (const float*)d_in[20];
  const float* A2 = (const float*)d_in[21];  const float* a2 = (const float*)d_in[22];
  const float* A3 = (const float*)d_in[23];  const float* a3 = (const float*)d_in[24];
  const float* cross_w = (const float*)d_in[25];
  const float* cross_b = (const float*)d_in[26];
  const float* D1 = (const float*)d_in[27];  const float* d1 = (const float*)d_in[28];
  const float* D2 = (const float*)d_in[29];  const float* d2 = (const float*)d_in[30];
  const float* D3 = (const float*)d_in[31];  const float* d3 = (const float*)d_in[32];
  const float* Wh = (const float*)d_in[33];  const float* bh = (const float*)d_in[34];

  float* base = (float*)d_ws;                           // B x 1664
  float* h1   = base + (size_t)Bn * FEATn;              // B x 512
  float* h2   = h1 + (size_t)Bn * 512;                  // B x 256
  float* h3   = h2 + (size_t)Bn * 256;                  // B x 256

  k_gather<<<Bn, 256, 0, stream>>>(user_cat, user_num, ctx_cat, ctx_num,
                                   item_cat, item_num, user_emb, item_emb, ctx_emb,
                                   Wu, bu, Wi, bi, Wc, bc, base);
  k_attn<<<Bn, 256, 0, stream>>>(hist_ids, hist_auth, hist_tag, hist_mask,
                                 item_emb, A1, a1, A2, a2, A3, a3, base);
  k_gemm<<<dim3(Bn / 64, 512 / 64), 256, 0, stream>>>(base, D1, d1, h1, 512, FEATn, 1);
  k_gemm<<<dim3(Bn / 64, 256 / 64), 256, 0, stream>>>(h1, D2, d2, h2, 256, 512, 1);
  k_gemm<<<dim3(Bn / 64, 256 / 64), 256, 0, stream>>>(h2, D3, d3, h3, 256, 256, 0);
  k_cross_final<<<Bn, 256, 0, stream>>>(base, cross_w, cross_b, h3, Wh, bh,
                                        (float*)d_out);
}

// Round 2
// 586.846 us; speedup vs baseline: 2.2260x; 2.2260x over previous
//
#include <hip/hip_runtime.h>
#include <math.h>

#define Bn   2048
#define Ln   200
#define En   64
#define Vn   100000
#define FEATn 1664
#define LT   32      // attention l sub-tile
#define LPAD 224     // 7 * 32
#define BPB  4       // batches per block in k_attn

typedef short s4v __attribute__((ext_vector_type(4)));
typedef short s8v __attribute__((ext_vector_type(8)));
typedef float f4v __attribute__((ext_vector_type(4)));

__device__ __forceinline__ short f2bf(float f) {
  union { float f; unsigned u; } v; v.f = f;
  unsigned r = v.u + 0x7FFFu + ((v.u >> 16) & 1u);   // RNE
  return (short)(r >> 16);
}
__device__ __forceinline__ float bf2f(short s) {
  union { unsigned u; float f; } v;
  v.u = ((unsigned)(unsigned short)s) << 16;
  return v.f;
}

// ---------------- block-wide reductions (256 threads = 4 waves) -------------
__device__ __forceinline__ float blk_sum(float v, float* shred) {
  #pragma unroll
  for (int o = 32; o > 0; o >>= 1) v += __shfl_down(v, o, 64);
  const int t = threadIdx.x;
  __syncthreads();
  if ((t & 63) == 0) shred[t >> 6] = v;
  __syncthreads();
  return shred[0] + shred[1] + shred[2] + shred[3];
}
__device__ __forceinline__ float blk_max(float v, float* shred) {
  #pragma unroll
  for (int o = 32; o > 0; o >>= 1) v = fmaxf(v, __shfl_down(v, o, 64));
  const int t = threadIdx.x;
  __syncthreads();
  if ((t & 63) == 0) shred[t >> 6] = v;
  __syncthreads();
  return fmaxf(fmaxf(shred[0], shred[1]), fmaxf(shred[2], shred[3]));
}

// ---------------- K1: small gathers + numeric projections -------------------
__global__ __launch_bounds__(256) void k_gather(
    const int* __restrict__ user_cat, const float* __restrict__ user_num,
    const int* __restrict__ ctx_cat,  const float* __restrict__ ctx_num,
    const int* __restrict__ item_cat, const float* __restrict__ item_num,
    const float* __restrict__ user_emb, const float* __restrict__ item_emb,
    const float* __restrict__ ctx_emb,
    const float* __restrict__ Wu, const float* __restrict__ bu,
    const float* __restrict__ Wi, const float* __restrict__ bi,
    const float* __restrict__ Wc, const float* __restrict__ bc,
    float* __restrict__ base)
{
  const int b = blockIdx.x;
  float* out = base + (size_t)b * FEATn;
  for (int f = threadIdx.x; f < 1344; f += 256) {
    float v;
    if (f < 384) {
      int n = f >> 6, e = f & 63;
      int id = user_cat[b * 6 + n];
      v = user_emb[((size_t)n * Vn + id) * 64 + e];
    } else if (f < 896) {
      int g = f - 384; int n = g >> 6, e = g & 63;
      int id = item_cat[b * 8 + n];
      v = item_emb[((size_t)n * Vn + id) * 64 + e];
    } else if (f < 1152) {
      int g = f - 896; int n = g >> 6, e = g & 63;
      int id = ctx_cat[b * 4 + n];
      v = ctx_emb[((size_t)n * Vn + id) * 64 + e];
    } else {
      int g = f - 1152; int wch = g >> 6, e = g & 63;
      float s;
      if (wch == 0) {
        s = bu[e];
        #pragma unroll
        for (int d = 0; d < 8; d++) s += user_num[b * 8 + d] * Wu[d * 64 + e];
      } else if (wch == 1) {
        s = bi[e];
        #pragma unroll
        for (int d = 0; d < 6; d++) s += item_num[b * 6 + d] * Wi[d * 64 + e];
      } else {
        s = bc[e];
        #pragma unroll
        for (int d = 0; d < 4; d++) s += ctx_num[b * 4 + d] * Wc[d * 64 + e];
      }
      v = fmaxf(s, 0.f);
    }
    out[f] = v;
  }
}

// ---------------- K2: fused DIN attention (bf16 MFMA) -----------------------
// 512 blocks x 4 b's. Per wave: layer1/2 weight B-fragments in registers.
// Folded layer-1: h1 = qterm + h@(A1[64:128]-A1[128:192]) + (q*h)@A1[192:256]
__global__ __launch_bounds__(256, 2) void k_attn(
    const int* __restrict__ hist_ids, const int* __restrict__ hist_author,
    const int* __restrict__ hist_tag, const int* __restrict__ hist_mask,
    const float* __restrict__ item_emb,
    const float* __restrict__ A1, const float* __restrict__ a1,
    const float* __restrict__ A2, const float* __restrict__ a2,
    const float* __restrict__ A3, const float* __restrict__ a3,
    float* __restrict__ base)
{
  const int t = threadIdx.x;
  const int w = t >> 6, lane = t & 63, ln = lane & 15, lg = lane >> 4;

  __shared__ short sA1s[16384] __attribute__((aligned(16)));  // A1sum bf16 [64][256]
  __shared__ short sX[4096]   __attribute__((aligned(16)));   // [32][128] swizzled
  __shared__ short sH1[8192]  __attribute__((aligned(16)));   // [32][256] swizzled
  __shared__ float sQ[64];
  __shared__ float sQT[256];
  __shared__ float sScore[LPAD];
  __shared__ float sMask[LPAD];
  __shared__ int   sHid[Ln];
  __shared__ float sPart[4][32];
  __shared__ float sRed[12][64];
  __shared__ float shred4[4];

  const float* item0 = item_emb;
  const float* itemA = item_emb + (size_t)Vn * 64;
  const float* itemT = item_emb + (size_t)7 * Vn * 64;

  // A1sum = A1[0:64] + A1[128:192]  (for qterm), bf16 in LDS
  for (int i = t; i < 16384; i += 256) {
    int e = i >> 8, j = i & 255;
    sA1s[i] = f2bf(A1[e * 256 + j] + A1[(128 + e) * 256 + j]);
  }

  // ---- per-wave weight fragments (registers) ----------------------------
  // k-mapping (same for A and B operands -> permutation-invariant):
  //   elems 0..3: k = 32*ks + 4*lg + j ; elems 4..7: +16
  s8v bw1[4][4];   // layer1: wave cols w*64 + nt*16 + ln, K=128
  #pragma unroll
  for (int nt = 0; nt < 4; nt++) {
    int col = w * 64 + nt * 16 + ln;
    #pragma unroll
    for (int ks = 0; ks < 4; ks++) {
      short e[8];
      #pragma unroll
      for (int jj = 0; jj < 8; jj++) {
        int k = ks * 32 + lg * 4 + (jj & 3) + ((jj >> 2) << 4);
        float v;
        if (ks < 2) v = A1[(64 + k) * 256 + col] - A1[(128 + k) * 256 + col];
        else        v = A1[(192 + (k - 64)) * 256 + col];
        e[jj] = f2bf(v);
      }
      bw1[nt][ks] = (s8v){e[0],e[1],e[2],e[3],e[4],e[5],e[6],e[7]};
    }
  }
  s8v bw2[2][8];   // layer2: wave cols w*32 + nt*16 + ln, K=256
  #pragma unroll
  for (int nt = 0; nt < 2; nt++) {
    int col = w * 32 + nt * 16 + ln;
    #pragma unroll
    for (int ks = 0; ks < 8; ks++) {
      short e[8];
      #pragma unroll
      for (int jj = 0; jj < 8; jj++) {
        int k = ks * 32 + lg * 4 + (jj & 3) + ((jj >> 2) << 4);
        e[jj] = f2bf(A2[k * 128 + col]);
      }
      bw2[nt][ks] = (s8v){e[0],e[1],e[2],e[3],e[4],e[5],e[6],e[7]};
    }
  }
  const float a1v = a1[t];
  const float a2v0 = a2[w * 32 + ln],      a2v1 = a2[w * 32 + 16 + ln];
  const float a3v0 = A3[w * 32 + ln],      a3v1 = A3[w * 32 + 16 + ln];
  const float a3s  = a3[0];

  for (int bi = 0; bi < BPB; bi++) {
    const int b = blockIdx.x * BPB + bi;
    __syncthreads();                       // LDS safe from previous b
    if (t < 64)  sQ[t] = base[(size_t)b * FEATn + 384 + t];
    if (t < LPAD) sMask[t] = (t < Ln && hist_mask[b * Ln + t] > 0) ? 1.f : 0.f;
    if (t < Ln)  sHid[t] = hist_ids[b * Ln + t];
    __syncthreads();

    { // qterm[j] = a1[j] + sum_e q[e] * A1sum[e][j]
      float s = a1v;
      #pragma unroll 8
      for (int e = 0; e < 64; e++) s += sQ[e] * bf2f(sA1s[e * 256 + t]);
      sQT[t] = s;
    }
    __syncthreads();
    const float qt0 = sQT[w * 64 + ln],      qt1 = sQT[w * 64 + 16 + ln];
    const float qt2 = sQT[w * 64 + 32 + ln], qt3 = sQT[w * 64 + 48 + ln];

    for (int l0 = 0; l0 < LPAD; l0 += LT) {
      // ---- build X tile [32][128] bf16, swizzled -----------------------
      {
        int row = t >> 3, c0 = (t & 7) << 3;
        int l = l0 + row;
        int id = sHid[(l < Ln) ? l : (Ln - 1)];
        const float* rp = item0 + (size_t)id * 64 + c0;
        float4 f0 = *(const float4*)rp, f1 = *(const float4*)(rp + 4);
        float q0 = sQ[c0+0], q1 = sQ[c0+1], q2 = sQ[c0+2], q3 = sQ[c0+3];
        float q4 = sQ[c0+4], q5 = sQ[c0+5], q6 = sQ[c0+6], q7 = sQ[c0+7];
        s8v hv = { f2bf(f0.x), f2bf(f0.y), f2bf(f0.z), f2bf(f0.w),
                   f2bf(f1.x), f2bf(f1.y), f2bf(f1.z), f2bf(f1.w) };
        s8v qv = { f2bf(f0.x*q0), f2bf(f0.y*q1), f2bf(f0.z*q2), f2bf(f0.w*q3),
                   f2bf(f1.x*q4), f2bf(f1.y*q5), f2bf(f1.z*q6), f2bf(f1.w*q7) };
        int swz = (row & 7) << 4;
        *(s8v*)(sX + ((row * 128 + c0) ^ swz))      = hv;
        *(s8v*)(sX + ((row * 128 + 64 + c0) ^ swz)) = qv;
      }
      __syncthreads();

      // ---- layer 1: 32x256 = X(32x128) @ W1eff, bias=qterm, relu --------
      f4v acc1[2][4];
      #pragma unroll
      for (int mt = 0; mt < 2; mt++) {
        acc1[mt][0] = (f4v){qt0, qt0, qt0, qt0};
        acc1[mt][1] = (f4v){qt1, qt1, qt1, qt1};
        acc1[mt][2] = (f4v){qt2, qt2, qt2, qt2};
        acc1[mt][3] = (f4v){qt3, qt3, qt3, qt3};
      }
      #pragma unroll
      for (int ks = 0; ks < 4; ks++) {
        s8v av[2];
        #pragma unroll
        for (int mt = 0; mt < 2; mt++) {
          int row = mt * 16 + ln;
          int bofs = row * 128 + ks * 32 + lg * 4;
          int swz = (ln & 7) << 4;
          s4v h0 = *(const s4v*)(sX + (bofs ^ swz));
          s4v h1 = *(const s4v*)(sX + ((bofs + 16) ^ swz));
          av[mt] = __builtin_shufflevector(h0, h1, 0,1,2,3,4,5,6,7);
        }
        #pragma unroll
        for (int mt = 0; mt < 2; mt++) {
          acc1[mt][0] = __builtin_amdgcn_mfma_f32_16x16x32_bf16(av[mt], bw1[0][ks], acc1[mt][0], 0, 0, 0);
          acc1[mt][1] = __builtin_amdgcn_mfma_f32_16x16x32_bf16(av[mt], bw1[1][ks], acc1[mt][1], 0, 0, 0);
          acc1[mt][2] = __builtin_amdgcn_mfma_f32_16x16x32_bf16(av[mt], bw1[2][ks], acc1[mt][2], 0, 0, 0);
          acc1[mt][3] = __builtin_amdgcn_mfma_f32_16x16x32_bf16(av[mt], bw1[3][ks], acc1[mt][3], 0, 0, 0);
        }
      }
      // relu -> sH1 (bf16, swizzled). D layout: row=4*lg+r, col=ln (verified)
      #pragma unroll
      for (int mt = 0; mt < 2; mt++)
        #pragma unroll
        for (int nt = 0; nt < 4; nt++)
          #pragma unroll
          for (int r = 0; r < 4; r++) {
            int row = mt * 16 + lg * 4 + r;
            int col = w * 64 + nt * 16 + ln;
            sH1[(row * 256 + col) ^ ((row & 7) << 4)] = f2bf(fmaxf(acc1[mt][nt][r], 0.f));
          }
      __syncthreads();

      // ---- layer 2: 32x128 = H1(32x256) @ A2, bias=a2, relu -------------
      f4v acc2[2][2];
      #pragma unroll
      for (int mt = 0; mt < 2; mt++) {
        acc2[mt][0] = (f4v){a2v0, a2v0, a2v0, a2v0};
        acc2[mt][1] = (f4v){a2v1, a2v1, a2v1, a2v1};
      }
      #pragma unroll
      for (int ks = 0; ks < 8; ks++) {
        #pragma unroll
        for (int mt = 0; mt < 2; mt++) {
          int row = mt * 16 + ln;
          int bofs = row * 256 + ks * 32 + lg * 4;
          int swz = (ln & 7) << 4;
          s4v h0 = *(const s4v*)(sH1 + (bofs ^ swz));
          s4v h1 = *(const s4v*)(sH1 + ((bofs + 16) ^ swz));
          s8v av = __builtin_shufflevector(h0, h1, 0,1,2,3,4,5,6,7);
          acc2[mt][0] = __builtin_amdgcn_mfma_f32_16x16x32_bf16(av, bw2[0][ks], acc2[mt][0], 0, 0, 0);
          acc2[mt][1] = __builtin_amdgcn_mfma_f32_16x16x32_bf16(av, bw2[1][ks], acc2[mt][1], 0, 0, 0);
        }
      }

      // ---- layer 3: score = relu(H2) @ A3 (per-wave partial over 32 cols)
      #pragma unroll
      for (int mt = 0; mt < 2; mt++) {
        #pragma unroll
        for (int r = 0; r < 4; r++) {
          float s = fmaxf(acc2[mt][0][r], 0.f) * a3v0 +
                    fmaxf(acc2[mt][1][r], 0.f) * a3v1;
          s += __shfl_xor(s, 1, 64);
          s += __shfl_xor(s, 2, 64);
          s += __shfl_xor(s, 4, 64);
          s += __shfl_xor(s, 8, 64);
          if (ln == 0) sPart[w][mt * 16 + lg * 4 + r] = s;
        }
      }
      __syncthreads();
      if (t < 32) sScore[l0 + t] = a3s + sPart[0][t] + sPart[1][t] + sPart[2][t] + sPart[3][t];
    }
    __syncthreads();

    // ---- softmax (masked) + renorm --------------------------------------
    float v = -3.0e38f;
    if (t < LPAD && sMask[t] > 0.f) v = sScore[t];
    float m = blk_max(v, shred4);
    float ev = 0.f;
    if (t < LPAD && sMask[t] > 0.f) ev = expf(sScore[t] - m);
    float S = blk_sum(ev, shred4);
    float nvalid = blk_sum((t < LPAD) ? sMask[t] : 0.f, shred4);
    float invS = 1.f / fmaxf(S, 1e-30f);
    if (t < LPAD) sScore[t] = ev * invS;      // sScore now holds w
    __syncthreads();

    // ---- hist_att + author/tag pools ------------------------------------
    {
      const int e = t & 63, wg = t >> 6;
      const int* haid = hist_author + b * Ln;
      const int* htid = hist_tag + b * Ln;
      float aw = 0.f, aa = 0.f, atg = 0.f;
      for (int l = wg; l < Ln; l += 4) {
        float mf = sMask[l];
        if (mf > 0.f) {
          float ww = sScore[l];
          aw  += ww * item0[(size_t)sHid[l] * 64 + e];
          aa  += itemA[(size_t)haid[l] * 64 + e];
          atg += itemT[(size_t)htid[l] * 64 + e];
        }
      }
      sRed[wg][e] = aw; sRed[4 + wg][e] = aa; sRed[8 + wg][e] = atg;
    }
    __syncthreads();
    if (t < 64) {
      float ha = 0.f, ap = 0.f, tp = 0.f;
      #pragma unroll
      for (int g = 0; g < 4; g++) {
        ha += sRed[g][t]; ap += sRed[4 + g][t]; tp += sRed[8 + g][t];
      }
      float inv = 1.f / fmaxf(nvalid, 1e-6f);
      ap *= inv; tp *= inv;
      float tv = sQ[t];
      float* out = base + (size_t)b * FEATn;
      out[1344 + t] = ha;
      out[1408 + t] = ap;
      out[1472 + t] = tp;
      out[1536 + t] = tv * ha;
      out[1600 + t] = tv - ha;
    }
  }
}

// ---------------- K3: generic fp32 tiled GEMM  C = act(A@W + bias) ----------
__global__ __launch_bounds__(256) void k_gemm(
    const float* __restrict__ A, const float* __restrict__ W,
    const float* __restrict__ bias, float* __restrict__ C,
    int N, int K, int relu)
{
  __shared__ float As[64][33];
  __shared__ float Ws[32][64];
  const int t = threadIdx.x;
  const int m0 = blockIdx.x * 64, n0 = blockIdx.y * 64;
  const int tx = t & 15, ty = t >> 4;
  float acc[4][4] = {{0.f}};

  for (int k0 = 0; k0 < K; k0 += 32) {
    #pragma unroll
    for (int i = 0; i < 2; i++) {
      int idx = t + i * 256;
      int r = idx >> 3, kq = (idx & 7) << 2;
      float4 a4 = *(const float4*)(A + (size_t)(m0 + r) * K + k0 + kq);
      As[r][kq + 0] = a4.x; As[r][kq + 1] = a4.y;
      As[r][kq + 2] = a4.z; As[r][kq + 3] = a4.w;
    }
    #pragma unroll
    for (int i = 0; i < 2; i++) {
      int idx = t + i * 256;
      int kk = idx >> 4, c4 = (idx & 15) << 2;
      float4 w4 = *(const float4*)(W + (size_t)(k0 + kk) * N + n0 + c4);
      *(float4*)&Ws[kk][c4] = w4;
    }
    __syncthreads();
    #pragma unroll
    for (int kk = 0; kk < 32; kk++) {
      float a0 = As[ty * 4 + 0][kk], a1v = As[ty * 4 + 1][kk];
      float a2v = As[ty * 4 + 2][kk], a3v = As[ty * 4 + 3][kk];
      float4 wv = *(const float4*)&Ws[kk][tx * 4];
      acc[0][0] += a0 * wv.x; acc[0][1] += a0 * wv.y; acc[0][2] += a0 * wv.z; acc[0][3] += a0 * wv.w;
      acc[1][0] += a1v * wv.x; acc[1][1] += a1v * wv.y; acc[1][2] += a1v * wv.z; acc[1][3] += a1v * wv.w;
      acc[2][0] += a2v * wv.x; acc[2][1] += a2v * wv.y; acc[2][2] += a2v * wv.z; acc[2][3] += a2v * wv.w;
      acc[3][0] += a3v * wv.x; acc[3][1] += a3v * wv.y; acc[3][2] += a3v * wv.z; acc[3][3] += a3v * wv.w;
    }
    __syncthreads();
  }
  float4 bz = *(const float4*)(bias + n0 + tx * 4);
  #pragma unroll
  for (int r = 0; r < 4; r++) {
    float4 o;
    o.x = acc[r][0] + bz.x; o.y = acc[r][1] + bz.y;
    o.z = acc[r][2] + bz.z; o.w = acc[r][3] + bz.w;
    if (relu) {
      o.x = fmaxf(o.x, 0.f); o.y = fmaxf(o.y, 0.f);
      o.z = fmaxf(o.z, 0.f); o.w = fmaxf(o.w, 0.f);
    }
    *(float4*)(C + (size_t)(m0 + ty * 4 + r) * N + n0 + tx * 4) = o;
  }
}

// ---------------- K4: DCN cross (3 iters) + final head ----------------------
__global__ __launch_bounds__(256) void k_cross_final(
    const float* __restrict__ base, const float* __restrict__ cross_w,
    const float* __restrict__ cross_b, const float* __restrict__ deep3,
    const float* __restrict__ Wh, const float* __restrict__ bh,
    float* __restrict__ out)
{
  __shared__ float shred[4];
  const int b = blockIdx.x, t = threadIdx.x;
  const float* br = base + (size_t)b * FEATn;
  float bs[7], xl[7];
  #pragma unroll
  for (int j = 0; j < 7; j++) {
    int i = t + j * 256;
    float v = (i < FEATn) ? br[i] : 0.f;
    bs[j] = v; xl[j] = v;
  }
  for (int k = 0; k < 3; k++) {
    float p = 0.f;
    #pragma unroll
    for (int j = 0; j < 7; j++) {
      int i = t + j * 256;
      if (i < FEATn) p += xl[j] * cross_w[k * FEATn + i];
    }
    float xw = blk_sum(p, shred);
    #pragma unroll
    for (int j = 0; j < 7; j++) {
      int i = t + j * 256;
      if (i < FEATn) xl[j] = bs[j] * xw + cross_b[k * FEATn + i] + xl[j];
    }
  }
  float p = 0.f;
  #pragma unroll
  for (int j = 0; j < 7; j++) {
    int i = t + j * 256;
    if (i < FEATn) p += xl[j] * Wh[i];
  }
  p += deep3[(size_t)b * 256 + t] * Wh[FEATn + t];
  float tot = blk_sum(p, shred);
  if (t == 0) out[b] = tot + bh[0];
}

// ---------------- launch -----------------------------------------------------
extern "C" void kernel_launch(void* const* d_in, const int* in_sizes, int n_in,
                              void* d_out, int out_size, void* d_ws, size_t ws_size,
                              hipStream_t stream) {
  (void)in_sizes; (void)n_in; (void)out_size; (void)ws_size;
  const int*   user_cat  = (const int*)d_in[0];
  const float* user_num  = (const float*)d_in[1];
  const int*   ctx_cat   = (const int*)d_in[2];
  const float* ctx_num   = (const float*)d_in[3];
  const int*   hist_ids  = (const int*)d_in[4];
  const int*   hist_auth = (const int*)d_in[5];
  const int*   hist_tag  = (const int*)d_in[6];
  const int*   hist_mask = (const int*)d_in[7];
  const int*   item_cat  = (const int*)d_in[8];
  const float* item_num  = (const float*)d_in[9];
  const float* user_emb  = (const float*)d_in[10];
  const float* item_emb  = (const float*)d_in[11];
  const float* ctx_emb   = (const float*)d_in[12];
  const float* Wu = (const float*)d_in[13];  const float* bu = (const float*)d_in[14];
  const float* Wi = (const float*)d_in[15];  const float* bi = (const float*)d_in[16];
  const float* Wc = (const float*)d_in[17];  const float* bc = (const float*)d_in[18];
  const float* A1 = (const float*)d_in[19];  const float* a1 = (const float*)d_in[20];
  const float* A2 = (const float*)d_in[21];  const float* a2 = (const float*)d_in[22];
  const float* A3 = (const float*)d_in[23];  const float* a3 = (const float*)d_in[24];
  const float* cross_w = (const float*)d_in[25];
  const float* cross_b = (const float*)d_in[26];
  const float* D1 = (const float*)d_in[27];  const float* d1 = (const float*)d_in[28];
  const float* D2 = (const float*)d_in[29];  const float* d2 = (const float*)d_in[30];
  const float* D3 = (const float*)d_in[31];  const float* d3 = (const float*)d_in[32];
  const float* Wh = (const float*)d_in[33];  const float* bh = (const float*)d_in[34];

  float* base = (float*)d_ws;                           // B x 1664
  float* h1   = base + (size_t)Bn * FEATn;              // B x 512
  float* h2   = h1 + (size_t)Bn * 512;                  // B x 256
  float* h3   = h2 + (size_t)Bn * 256;                  // B x 256

  k_gather<<<Bn, 256, 0, stream>>>(user_cat, user_num, ctx_cat, ctx_num,
                                   item_cat, item_num, user_emb, item_emb, ctx_emb,
                                   Wu, bu, Wi, bi, Wc, bc, base);
  k_attn<<<Bn / BPB, 256, 0, stream>>>(hist_ids, hist_auth, hist_tag, hist_mask,
                                       item_emb, A1, a1, A2, a2, A3, a3, base);
  k_gemm<<<dim3(Bn / 64, 512 / 64), 256, 0, stream>>>(base, D1, d1, h1, 512, FEATn, 1);
  k_gemm<<<dim3(Bn / 64, 256 / 64), 256, 0, stream>>>(h1, D2, d2, h2, 256, 512, 1);
  k_gemm<<<dim3(Bn / 64, 256 / 64), 256, 0, stream>>>(h2, D3, d3, h3, 256, 256, 0);
  k_cross_final<<<Bn, 256, 0, stream>>>(base, cross_w, cross_b, h3, Wh, bh,
                                        (float*)d_out);
}

// Round 3
// 459.895 us; speedup vs baseline: 2.8404x; 1.2760x over previous
//
#include <hip/hip_runtime.h>
#include <math.h>

#define Bn   2048
#define Ln   200
#define En   64
#define Vn   100000
#define FEATn 1664
#define LT   32
#define LPAD 224     // 7 * 32
#define BPB  2       // batches per block in k_attn

typedef short s4v __attribute__((ext_vector_type(4)));
typedef short s8v __attribute__((ext_vector_type(8)));
typedef float f4v __attribute__((ext_vector_type(4)));

__device__ __forceinline__ short f2bf(float f) {
  union { float f; unsigned u; } v; v.f = f;
  unsigned r = v.u + 0x7FFFu + ((v.u >> 16) & 1u);   // RNE
  return (short)(r >> 16);
}
__device__ __forceinline__ float bf2f(short s) {
  union { unsigned u; float f; } v;
  v.u = ((unsigned)(unsigned short)s) << 16;
  return v.f;
}

// fragment k-mapping shared by prep (B-side) and attn (A-side):
// k = ks*32 + lg*4 + (jj&3) + ((jj>>2)<<4)
__device__ __forceinline__ int frag_k(int ks, int lg, int jj) {
  return ks * 32 + lg * 4 + (jj & 3) + ((jj >> 2) << 4);
}

// ---------------- block-wide reductions (256 threads = 4 waves) -------------
__device__ __forceinline__ float blk_sum(float v, float* shred) {
  #pragma unroll
  for (int o = 32; o > 0; o >>= 1) v += __shfl_down(v, o, 64);
  const int t = threadIdx.x;
  __syncthreads();
  if ((t & 63) == 0) shred[t >> 6] = v;
  __syncthreads();
  return shred[0] + shred[1] + shred[2] + shred[3];
}
__device__ __forceinline__ float blk_max(float v, float* shred) {
  #pragma unroll
  for (int o = 32; o > 0; o >>= 1) v = fmaxf(v, __shfl_down(v, o, 64));
  const int t = threadIdx.x;
  __syncthreads();
  if ((t & 63) == 0) shred[t >> 6] = v;
  __syncthreads();
  return fmaxf(fmaxf(shred[0], shred[1]), fmaxf(shred[2], shred[3]));
}

// ---------------- K0: prep — fragment-ordered bf16 weights ------------------
// W1f: 32768 shorts. idx bits: w[14:13] ks[12:11] nt[10:9] lane[8:3] jj[2:0]
// W2f: 32768 shorts. idx bits: w[14:13] ks[12:10] nt[9] lane[8:3] jj[2:0]
// A1s: 16384 shorts  (A1[0:64] + A1[128:192], row-major 64x256)
__global__ __launch_bounds__(256) void k_prep(
    const float* __restrict__ A1, const float* __restrict__ A2,
    short* __restrict__ W1f, short* __restrict__ W2f, short* __restrict__ A1s)
{
  int i = blockIdx.x * 256 + threadIdx.x;
  if (i < 32768) {
    int jj = i & 7, lane = (i >> 3) & 63, nt = (i >> 9) & 3,
        ks = (i >> 11) & 3, w = (i >> 13) & 3;
    int col = w * 64 + nt * 16 + (lane & 15);
    int lg = lane >> 4;
    float v;
    if (ks < 2) {
      int k = frag_k(ks, lg, jj);
      v = A1[(64 + k) * 256 + col] - A1[(128 + k) * 256 + col];
    } else {
      int k = frag_k(ks - 2, lg, jj);
      v = A1[(192 + k) * 256 + col];
    }
    W1f[i] = f2bf(v);
  } else if (i < 65536) {
    int u = i - 32768;
    int jj = u & 7, lane = (u >> 3) & 63, nt = (u >> 9) & 1,
        ks = (u >> 10) & 7, w = (u >> 13) & 3;
    int col = w * 32 + nt * 16 + (lane & 15);
    int lg = lane >> 4;
    int k = frag_k(ks, lg, jj);
    W2f[u] = f2bf(A2[k * 128 + col]);
  } else if (i < 81920) {
    int u = i - 65536;
    int e = u >> 8, j = u & 255;
    A1s[u] = f2bf(A1[e * 256 + j] + A1[(128 + e) * 256 + j]);
  }
}

// ---------------- K1: small gathers + numeric proj + author/tag pools -------
__global__ __launch_bounds__(256) void k_gather(
    const int* __restrict__ user_cat, const float* __restrict__ user_num,
    const int* __restrict__ ctx_cat,  const float* __restrict__ ctx_num,
    const int* __restrict__ item_cat, const float* __restrict__ item_num,
    const float* __restrict__ user_emb, const float* __restrict__ item_emb,
    const float* __restrict__ ctx_emb,
    const float* __restrict__ Wu, const float* __restrict__ bu,
    const float* __restrict__ Wi, const float* __restrict__ bi,
    const float* __restrict__ Wc, const float* __restrict__ bc,
    const int* __restrict__ hist_author, const int* __restrict__ hist_tag,
    const int* __restrict__ hist_mask,
    float* __restrict__ base)
{
  __shared__ float sRed[8][64];
  __shared__ float sNv[4];
  const int b = blockIdx.x, t = threadIdx.x;
  float* out = base + (size_t)b * FEATn;

  for (int f = t; f < 1344; f += 256) {
    float v;
    if (f < 384) {
      int n = f >> 6, e = f & 63;
      int id = user_cat[b * 6 + n];
      v = user_emb[((size_t)n * Vn + id) * 64 + e];
    } else if (f < 896) {
      int g = f - 384; int n = g >> 6, e = g & 63;
      int id = item_cat[b * 8 + n];
      v = item_emb[((size_t)n * Vn + id) * 64 + e];
    } else if (f < 1152) {
      int g = f - 896; int n = g >> 6, e = g & 63;
      int id = ctx_cat[b * 4 + n];
      v = ctx_emb[((size_t)n * Vn + id) * 64 + e];
    } else {
      int g = f - 1152; int wch = g >> 6, e = g & 63;
      float s;
      if (wch == 0) {
        s = bu[e];
        #pragma unroll
        for (int d = 0; d < 8; d++) s += user_num[b * 8 + d] * Wu[d * 64 + e];
      } else if (wch == 1) {
        s = bi[e];
        #pragma unroll
        for (int d = 0; d < 6; d++) s += item_num[b * 6 + d] * Wi[d * 64 + e];
      } else {
        s = bc[e];
        #pragma unroll
        for (int d = 0; d < 4; d++) s += ctx_num[b * 4 + d] * Wc[d * 64 + e];
      }
      v = fmaxf(s, 0.f);
    }
    out[f] = v;
  }

  // author/tag mean pools (independent of attention scores)
  const float* itemA = item_emb + (size_t)Vn * 64;
  const float* itemT = item_emb + (size_t)7 * Vn * 64;
  const int e = t & 63, wg = t >> 6;
  float aa = 0.f, tg = 0.f, nv = 0.f;
  for (int l = wg; l < Ln; l += 4) {
    if (hist_mask[b * Ln + l] > 0) {      // wave-uniform
      aa += itemA[(size_t)hist_author[b * Ln + l] * 64 + e];
      tg += itemT[(size_t)hist_tag[b * Ln + l] * 64 + e];
      nv += 1.f;
    }
  }
  sRed[wg][e] = aa; sRed[4 + wg][e] = tg;
  if (e == 0) sNv[wg] = nv;
  __syncthreads();
  if (t < 64) {
    float ap = sRed[0][t] + sRed[1][t] + sRed[2][t] + sRed[3][t];
    float tp = sRed[4][t] + sRed[5][t] + sRed[6][t] + sRed[7][t];
    float nvalid = sNv[0] + sNv[1] + sNv[2] + sNv[3];
    float inv = 1.f / fmaxf(nvalid, 1e-6f);
    out[1408 + t] = ap * inv;
    out[1472 + t] = tp * inv;
  }
}

// ---------------- K1b: qterm[b][256] = a1 + q @ A1sum ------------------------
__global__ __launch_bounds__(256) void k_qterm(
    const float* __restrict__ base, const short* __restrict__ A1s,
    const float* __restrict__ a1, float* __restrict__ qterm)
{
  __shared__ float sQ[64];
  const int b = blockIdx.x, t = threadIdx.x;
  if (t < 64) sQ[t] = base[(size_t)b * FEATn + 384 + t];
  __syncthreads();
  float s = a1[t];
  #pragma unroll 8
  for (int e = 0; e < 64; e++) s += sQ[e] * bf2f(A1s[e * 256 + t]);
  qterm[(size_t)b * 256 + t] = s;
}

// ---------------- K2: fused DIN attention (bf16 MFMA, single-gather) --------
__global__ __launch_bounds__(256, 2) void k_attn(
    const int* __restrict__ hist_ids, const int* __restrict__ hist_mask,
    const float* __restrict__ item_emb,
    const short* __restrict__ W1f, const short* __restrict__ W2f,
    const float* __restrict__ qterm,
    const float* __restrict__ a2, const float* __restrict__ A3,
    const float* __restrict__ a3,
    float* __restrict__ base)
{
  const int t = threadIdx.x;
  const int w = t >> 6, lane = t & 63, ln = lane & 15, lg = lane >> 4;

  __shared__ short sH[LPAD * 64] __attribute__((aligned(16)));  // 28 KB, swizzled
  __shared__ short sH1[32 * 256] __attribute__((aligned(16)));  // 16 KB, swizzled
  __shared__ float sQ[64];
  __shared__ float sScore[LPAD];
  __shared__ float sMask[LPAD];
  __shared__ int   sHid[LPAD];
  __shared__ float sPart[4][32];
  __shared__ float sRed[4][64];
  __shared__ float shred4[4];

  const float* item0 = item_emb;   // table 0

  // ---- weight fragments: coalesced s8v loads from fragment-ordered arrays --
  s8v bw1h[2][4], bw1q[2][4], bw2[8][2];
  #pragma unroll
  for (int ks = 0; ks < 4; ks++)
    #pragma unroll
    for (int nt = 0; nt < 4; nt++) {
      s8v f = *(const s8v*)(W1f + (((w * 4 + ks) * 4 + nt) << 9) + lane * 8);
      if (ks < 2) bw1h[ks][nt] = f; else bw1q[ks - 2][nt] = f;
    }
  #pragma unroll
  for (int ks = 0; ks < 8; ks++)
    #pragma unroll
    for (int nt = 0; nt < 2; nt++)
      bw2[ks][nt] = *(const s8v*)(W2f + (((w * 8 + ks) * 2 + nt) << 9) + lane * 8);

  const float a2v0 = a2[w * 32 + ln], a2v1 = a2[w * 32 + 16 + ln];
  const float a3v0 = A3[w * 32 + ln], a3v1 = A3[w * 32 + 16 + ln];
  const float a3s  = a3[0];

  for (int bi = 0; bi < BPB; bi++) {
    const int b = blockIdx.x * BPB + bi;
    __syncthreads();                      // protect LDS from previous b
    if (t < 64)  sQ[t] = base[(size_t)b * FEATn + 384 + t];
    if (t < LPAD) {
      sMask[t] = (t < Ln && hist_mask[b * Ln + t] > 0) ? 1.f : 0.f;
      sHid[t]  = (t < Ln) ? hist_ids[b * Ln + t] : 0;
    }
    __syncthreads();

    // per-lane q multipliers + qterm bias
    float qk[2][8];
    #pragma unroll
    for (int ks = 0; ks < 2; ks++)
      #pragma unroll
      for (int jj = 0; jj < 8; jj++) qk[ks][jj] = sQ[frag_k(ks, lg, jj)];
    float qt[4];
    #pragma unroll
    for (int i = 0; i < 4; i++)
      qt[i] = qterm[(size_t)b * 256 + w * 64 + i * 16 + ln];

    // ---- single gather of all history rows -> sH (bf16, swizzled) --------
    for (int u = t; u < LPAD * 8; u += 256) {
      int row = u >> 3, seg = u & 7;
      s8v hv = (s8v){0,0,0,0,0,0,0,0};
      if (row < Ln) {
        const float* rp = item0 + (size_t)sHid[row] * 64 + seg * 8;
        float4 f0 = *(const float4*)rp, f1 = *(const float4*)(rp + 4);
        hv = (s8v){ f2bf(f0.x), f2bf(f0.y), f2bf(f0.z), f2bf(f0.w),
                    f2bf(f1.x), f2bf(f1.y), f2bf(f1.z), f2bf(f1.w) };
      }
      *(s8v*)(sH + ((row * 64 + seg * 8) ^ ((row & 7) << 3))) = hv;
    }
    __syncthreads();

    for (int l0 = 0; l0 < LPAD; l0 += LT) {
      // ---- layer 1: h-frag from sH + q*h-frag in registers ----------------
      f4v acc1[2][4];
      #pragma unroll
      for (int mt = 0; mt < 2; mt++)
        #pragma unroll
        for (int nt = 0; nt < 4; nt++)
          acc1[mt][nt] = (f4v){qt[nt], qt[nt], qt[nt], qt[nt]};

      #pragma unroll
      for (int ks = 0; ks < 2; ks++) {
        #pragma unroll
        for (int mt = 0; mt < 2; mt++) {
          int row = l0 + mt * 16 + ln;
          int idx = row * 64 + ks * 32 + lg * 4;
          int swz = (row & 7) << 3;
          s4v h0 = *(const s4v*)(sH + (idx ^ swz));
          s4v h1 = *(const s4v*)(sH + ((idx + 16) ^ swz));
          s8v hf = __builtin_shufflevector(h0, h1, 0,1,2,3,4,5,6,7);
          s8v qf;
          #pragma unroll
          for (int jj = 0; jj < 8; jj++) qf[jj] = f2bf(bf2f(hf[jj]) * qk[ks][jj]);
          #pragma unroll
          for (int nt = 0; nt < 4; nt++)
            acc1[mt][nt] = __builtin_amdgcn_mfma_f32_16x16x32_bf16(hf, bw1h[ks][nt], acc1[mt][nt], 0, 0, 0);
          #pragma unroll
          for (int nt = 0; nt < 4; nt++)
            acc1[mt][nt] = __builtin_amdgcn_mfma_f32_16x16x32_bf16(qf, bw1q[ks][nt], acc1[mt][nt], 0, 0, 0);
        }
      }
      // relu -> sH1 (bf16, swizzled)
      #pragma unroll
      for (int mt = 0; mt < 2; mt++)
        #pragma unroll
        for (int nt = 0; nt < 4; nt++)
          #pragma unroll
          for (int r = 0; r < 4; r++) {
            int row = mt * 16 + lg * 4 + r;
            int col = w * 64 + nt * 16 + ln;
            sH1[(row * 256 + col) ^ ((row & 7) << 3)] = f2bf(fmaxf(acc1[mt][nt][r], 0.f));
          }
      __syncthreads();

      // ---- layer 2 -------------------------------------------------------
      f4v acc2[2][2];
      #pragma unroll
      for (int mt = 0; mt < 2; mt++) {
        acc2[mt][0] = (f4v){a2v0, a2v0, a2v0, a2v0};
        acc2[mt][1] = (f4v){a2v1, a2v1, a2v1, a2v1};
      }
      #pragma unroll
      for (int ks = 0; ks < 8; ks++) {
        #pragma unroll
        for (int mt = 0; mt < 2; mt++) {
          int row = mt * 16 + ln;
          int idx = row * 256 + ks * 32 + lg * 4;
          int swz = (row & 7) << 3;
          s4v h0 = *(const s4v*)(sH1 + (idx ^ swz));
          s4v h1 = *(const s4v*)(sH1 + ((idx + 16) ^ swz));
          s8v af = __builtin_shufflevector(h0, h1, 0,1,2,3,4,5,6,7);
          acc2[mt][0] = __builtin_amdgcn_mfma_f32_16x16x32_bf16(af, bw2[ks][0], acc2[mt][0], 0, 0, 0);
          acc2[mt][1] = __builtin_amdgcn_mfma_f32_16x16x32_bf16(af, bw2[ks][1], acc2[mt][1], 0, 0, 0);
        }
      }

      // ---- layer 3: per-wave partial over this wave's 32 cols --------------
      #pragma unroll
      for (int mt = 0; mt < 2; mt++) {
        #pragma unroll
        for (int r = 0; r < 4; r++) {
          float s = fmaxf(acc2[mt][0][r], 0.f) * a3v0 +
                    fmaxf(acc2[mt][1][r], 0.f) * a3v1;
          s += __shfl_xor(s, 1, 64);
          s += __shfl_xor(s, 2, 64);
          s += __shfl_xor(s, 4, 64);
          s += __shfl_xor(s, 8, 64);
          if (ln == 0) sPart[w][mt * 16 + lg * 4 + r] = s;
        }
      }
      __syncthreads();
      if (t < 32) sScore[l0 + t] = a3s + sPart[0][t] + sPart[1][t] + sPart[2][t] + sPart[3][t];
    }
    __syncthreads();

    // ---- softmax (masked) ------------------------------------------------
    float v = -3.0e38f;
    if (t < LPAD && sMask[t] > 0.f) v = sScore[t];
    float m = blk_max(v, shred4);
    float ev = 0.f;
    if (t < LPAD && sMask[t] > 0.f) ev = expf(sScore[t] - m);
    float S = blk_sum(ev, shred4);
    float invS = 1.f / fmaxf(S, 1e-30f);
    if (t < LPAD) sScore[t] = ev * invS;
    __syncthreads();

    // ---- hist_att from LDS (sH) ------------------------------------------
    {
      const int e = t & 63, wg = t >> 6;
      float aw = 0.f;
      for (int l = wg; l < Ln; l += 4) {
        if (sMask[l] > 0.f)
          aw += sScore[l] * bf2f(sH[(l * 64 + e) ^ ((l & 7) << 3)]);
      }
      sRed[wg][e] = aw;
    }
    __syncthreads();
    if (t < 64) {
      float ha = sRed[0][t] + sRed[1][t] + sRed[2][t] + sRed[3][t];
      float tv = sQ[t];
      float* out = base + (size_t)b * FEATn;
      out[1344 + t] = ha;
      out[1536 + t] = tv * ha;
      out[1600 + t] = tv - ha;
    }
  }
}

// ---------------- K3: generic fp32 tiled GEMM  C = act(A@W + bias) ----------
__global__ __launch_bounds__(256) void k_gemm(
    const float* __restrict__ A, const float* __restrict__ W,
    const float* __restrict__ bias, float* __restrict__ C,
    int N, int K, int relu)
{
  __shared__ float As[64][33];
  __shared__ float Ws[32][64];
  const int t = threadIdx.x;
  const int m0 = blockIdx.x * 64, n0 = blockIdx.y * 64;
  const int tx = t & 15, ty = t >> 4;
  float acc[4][4] = {{0.f}};

  for (int k0 = 0; k0 < K; k0 += 32) {
    #pragma unroll
    for (int i = 0; i < 2; i++) {
      int idx = t + i * 256;
      int r = idx >> 3, kq = (idx & 7) << 2;
      float4 a4 = *(const float4*)(A + (size_t)(m0 + r) * K + k0 + kq);
      As[r][kq + 0] = a4.x; As[r][kq + 1] = a4.y;
      As[r][kq + 2] = a4.z; As[r][kq + 3] = a4.w;
    }
    #pragma unroll
    for (int i = 0; i < 2; i++) {
      int idx = t + i * 256;
      int kk = idx >> 4, c4 = (idx & 15) << 2;
      float4 w4 = *(const float4*)(W + (size_t)(k0 + kk) * N + n0 + c4);
      *(float4*)&Ws[kk][c4] = w4;
    }
    __syncthreads();
    #pragma unroll
    for (int kk = 0; kk < 32; kk++) {
      float a0 = As[ty * 4 + 0][kk], a1v = As[ty * 4 + 1][kk];
      float a2v = As[ty * 4 + 2][kk], a3v = As[ty * 4 + 3][kk];
      float4 wv = *(const float4*)&Ws[kk][tx * 4];
      acc[0][0] += a0 * wv.x; acc[0][1] += a0 * wv.y; acc[0][2] += a0 * wv.z; acc[0][3] += a0 * wv.w;
      acc[1][0] += a1v * wv.x; acc[1][1] += a1v * wv.y; acc[1][2] += a1v * wv.z; acc[1][3] += a1v * wv.w;
      acc[2][0] += a2v * wv.x; acc[2][1] += a2v * wv.y; acc[2][2] += a2v * wv.z; acc[2][3] += a2v * wv.w;
      acc[3][0] += a3v * wv.x; acc[3][1] += a3v * wv.y; acc[3][2] += a3v * wv.z; acc[3][3] += a3v * wv.w;
    }
    __syncthreads();
  }
  float4 bz = *(const float4*)(bias + n0 + tx * 4);
  #pragma unroll
  for (int r = 0; r < 4; r++) {
    float4 o;
    o.x = acc[r][0] + bz.x; o.y = acc[r][1] + bz.y;
    o.z = acc[r][2] + bz.z; o.w = acc[r][3] + bz.w;
    if (relu) {
      o.x = fmaxf(o.x, 0.f); o.y = fmaxf(o.y, 0.f);
      o.z = fmaxf(o.z, 0.f); o.w = fmaxf(o.w, 0.f);
    }
    *(float4*)(C + (size_t)(m0 + ty * 4 + r) * N + n0 + tx * 4) = o;
  }
}

// ---------------- K4: DCN cross (3 iters) + final head ----------------------
__global__ __launch_bounds__(256) void k_cross_final(
    const float* __restrict__ base, const float* __restrict__ cross_w,
    const float* __restrict__ cross_b, const float* __restrict__ deep3,
    const float* __restrict__ Wh, const float* __restrict__ bh,
    float* __restrict__ out)
{
  __shared__ float shred[4];
  const int b = blockIdx.x, t = threadIdx.x;
  const float* br = base + (size_t)b * FEATn;
  float bs[7], xl[7];
  #pragma unroll
  for (int j = 0; j < 7; j++) {
    int i = t + j * 256;
    float v = (i < FEATn) ? br[i] : 0.f;
    bs[j] = v; xl[j] = v;
  }
  for (int k = 0; k < 3; k++) {
    float p = 0.f;
    #pragma unroll
    for (int j = 0; j < 7; j++) {
      int i = t + j * 256;
      if (i < FEATn) p += xl[j] * cross_w[k * FEATn + i];
    }
    float xw = blk_sum(p, shred);
    #pragma unroll
    for (int j = 0; j < 7; j++) {
      int i = t + j * 256;
      if (i < FEATn) xl[j] = bs[j] * xw + cross_b[k * FEATn + i] + xl[j];
    }
  }
  float p = 0.f;
  #pragma unroll
  for (int j = 0; j < 7; j++) {
    int i = t + j * 256;
    if (i < FEATn) p += xl[j] * Wh[i];
  }
  p += deep3[(size_t)b * 256 + t] * Wh[FEATn + t];
  float tot = blk_sum(p, shred);
  if (t == 0) out[b] = tot + bh[0];
}

// ---------------- launch -----------------------------------------------------
extern "C" void kernel_launch(void* const* d_in, const int* in_sizes, int n_in,
                              void* d_out, int out_size, void* d_ws, size_t ws_size,
                              hipStream_t stream) {
  (void)in_sizes; (void)n_in; (void)out_size; (void)ws_size;
  const int*   user_cat  = (const int*)d_in[0];
  const float* user_num  = (const float*)d_in[1];
  const int*   ctx_cat   = (const int*)d_in[2];
  const float* ctx_num   = (const float*)d_in[3];
  const int*   hist_ids  = (const int*)d_in[4];
  const int*   hist_auth = (const int*)d_in[5];
  const int*   hist_tag  = (const int*)d_in[6];
  const int*   hist_mask = (const int*)d_in[7];
  const int*   item_cat  = (const int*)d_in[8];
  const float* item_num  = (const float*)d_in[9];
  const float* user_emb  = (const float*)d_in[10];
  const float* item_emb  = (const float*)d_in[11];
  const float* ctx_emb   = (const float*)d_in[12];
  const float* Wu = (const float*)d_in[13];  const float* bu = (const float*)d_in[14];
  const float* Wi = (const float*)d_in[15];  const float* bi = (const float*)d_in[16];
  const float* Wc = (const float*)d_in[17];  const float* bc = (const float*)d_in[18];
  const float* A1 = (const float*)d_in[19];  const float* a1 = (const float*)d_in[20];
  const float* A2 = (const float*)d_in[21];  const float* a2 = (const float*)d_in[22];
  const float* A3 = (const float*)d_in[23];  const float* a3 = (const float*)d_in[24];
  const float* cross_w = (const float*)d_in[25];
  const float* cross_b = (const float*)d_in[26];
  const float* D1 = (const float*)d_in[27];  const float* d1 = (const float*)d_in[28];
  const float* D2 = (const float*)d_in[29];  const float* d2 = (const float*)d_in[30];
  const float* D3 = (const float*)d_in[31];  const float* d3 = (const float*)d_in[32];
  const float* Wh = (const float*)d_in[33];  const float* bh = (const float*)d_in[34];

  float* base  = (float*)d_ws;                          // B x 1664
  float* h1    = base + (size_t)Bn * FEATn;             // B x 512
  float* h2    = h1 + (size_t)Bn * 512;                 // B x 256
  float* h3    = h2 + (size_t)Bn * 256;                 // B x 256
  float* qterm = h3 + (size_t)Bn * 256;                 // B x 256
  short* W1f   = (short*)(qterm + (size_t)Bn * 256);    // 32768
  short* W2f   = W1f + 32768;                           // 32768
  short* A1s   = W2f + 32768;                           // 16384

  k_prep<<<320, 256, 0, stream>>>(A1, A2, W1f, W2f, A1s);
  k_gather<<<Bn, 256, 0, stream>>>(user_cat, user_num, ctx_cat, ctx_num,
                                   item_cat, item_num, user_emb, item_emb, ctx_emb,
                                   Wu, bu, Wi, bi, Wc, bc,
                                   hist_auth, hist_tag, hist_mask, base);
  k_qterm<<<Bn, 256, 0, stream>>>(base, A1s, a1, qterm);
  k_attn<<<Bn / BPB, 256, 0, stream>>>(hist_ids, hist_mask, item_emb,
                                       W1f, W2f, qterm, a2, A3, a3, base);
  k_gemm<<<dim3(Bn / 64, 512 / 64), 256, 0, stream>>>(base, D1, d1, h1, 512, FEATn, 1);
  k_gemm<<<dim3(Bn / 64, 256 / 64), 256, 0, stream>>>(h1, D2, d2, h2, 256, 512, 1);
  k_gemm<<<dim3(Bn / 64, 256 / 64), 256, 0, stream>>>(h2, D3, d3, h3, 256, 256, 0);
  k_cross_final<<<Bn, 256, 0, stream>>>(base, cross_w, cross_b, h3, Wh, bh,
                                        (float*)d_out);
}